// Round 9
// baseline (2542.870 us; speedup 1.0000x reference)
//
#include <hip/hip_runtime.h>

#define V_N   200000
#define E_N   600000
#define FEAT  960
#define HDIM  128
#define NREST 7
#define NSCAN 196   // ceil(V_N/1024)

typedef __attribute__((ext_vector_type(8))) short bf16x8;
typedef __attribute__((ext_vector_type(4))) float f32x4;

__device__ __forceinline__ unsigned short f2bf(float f) {
    unsigned u = __builtin_bit_cast(unsigned, f);
    unsigned r = (u + 0x7FFFu + ((u >> 16) & 1u)) >> 16;
    return (unsigned short)r;
}
__device__ __forceinline__ float bf2f(unsigned h) {
    unsigned u = h << 16;
    return __builtin_bit_cast(float, u);
}

// async global->LDS, 16B per lane; LDS dest wave-uniform base + lane*16.
__device__ __forceinline__ void gload_lds16(const void* g, void* l) {
    __builtin_amdgcn_global_load_lds(
        (const __attribute__((address_space(1))) void*)g,
        (__attribute__((address_space(3))) void*)l, 16, 0, 0);
}

__device__ __forceinline__ void acc8(float* a, uint4 q) {
    a[0] += bf2f(q.x & 0xffffu); a[1] += bf2f(q.x >> 16);
    a[2] += bf2f(q.y & 0xffffu); a[3] += bf2f(q.y >> 16);
    a[4] += bf2f(q.z & 0xffffu); a[5] += bf2f(q.z >> 16);
    a[6] += bf2f(q.w & 0xffffu); a[7] += bf2f(q.w >> 16);
}

// ---------------------------------------------------------------------------
// Backbone MFMA GEMM: C = relu(A(fp32) @ B^T + bias), BM=BN=128, BK=64.
// ---------------------------------------------------------------------------
template<int KT>
__global__ __launch_bounds__(256) void backbone_mfma_kernel(
    const float* __restrict__ A, int lda,
    const short* __restrict__ B, int ldb,
    const float* __restrict__ bias,
    short* __restrict__ C, int ldc)
{
    __shared__ short Smem[128 * 128];
    short* As = Smem;
    short* Bs = Smem + 128 * 64;
    const int tid = threadIdx.x;
    const int bm0 = blockIdx.x * 128;
    const int wid = tid >> 6, lane = tid & 63;
    const int wm = wid >> 1, wn = wid & 1;
    const int srow = wid * 32 + (lane >> 3);
    const int sc   = lane & 7;

    f32x4 acc[4][4];
    #pragma unroll
    for (int n = 0; n < 4; ++n) {
        float bv = bias[wn * 64 + n * 16 + (lane & 15)];
        #pragma unroll
        for (int m = 0; m < 4; ++m)
            acc[m][n] = (f32x4){bv, bv, bv, bv};
    }

    for (int it = 0; it < KT; ++it) {
        const int k0 = it * 64;
        __syncthreads();
        #pragma unroll
        for (int i = 0; i < 8; ++i) {
            int c = i * 256 + tid;
            int row = c >> 4, c4 = c & 15;
            int grow = bm0 + row; if (grow >= V_N) grow = V_N - 1;
            float4 t = *(const float4*)(A + (size_t)grow * lda + k0 + c4 * 4);
            unsigned lo = (unsigned)f2bf(t.x) | ((unsigned)f2bf(t.y) << 16);
            unsigned hi = (unsigned)f2bf(t.z) | ((unsigned)f2bf(t.w) << 16);
            int e = (row * 64 + c4 * 4) ^ ((row & 7) << 3);
            *(uint2*)&As[e] = make_uint2(lo, hi);
        }
        #pragma unroll
        for (int i = 0; i < 4; ++i) {
            int row = srow + i * 8;
            int g = (sc ^ (row & 7)) << 3;
            gload_lds16(B + (size_t)row * ldb + k0 + g, Bs + (wid * 32 + i * 8) * 64);
        }
        __syncthreads();
        #pragma unroll
        for (int kk = 0; kk < 2; ++kk) {
            bf16x8 a[4], b[4];
            #pragma unroll
            for (int m = 0; m < 4; ++m) {
                int row = wm * 64 + m * 16 + (lane & 15);
                int e = (row * 64 + kk * 32 + (lane >> 4) * 8) ^ ((row & 7) << 3);
                a[m] = *(const bf16x8*)&As[e];
            }
            #pragma unroll
            for (int n = 0; n < 4; ++n) {
                int row = wn * 64 + n * 16 + (lane & 15);
                int e = (row * 64 + kk * 32 + (lane >> 4) * 8) ^ ((row & 7) << 3);
                b[n] = *(const bf16x8*)&Bs[e];
            }
            #pragma unroll
            for (int m = 0; m < 4; ++m)
                #pragma unroll
                for (int n = 0; n < 4; ++n)
                    acc[m][n] = __builtin_amdgcn_mfma_f32_16x16x32_bf16(
                        a[m], b[n], acc[m][n], 0, 0, 0);
        }
    }

    __syncthreads();
    #pragma unroll
    for (int m = 0; m < 4; ++m) {
        #pragma unroll
        for (int j = 0; j < 4; ++j) {
            int row = wm * 64 + m * 16 + (lane >> 4) * 4 + j;
            #pragma unroll
            for (int n = 0; n < 4; ++n) {
                int colx = wn * 64 + n * 16 + (lane & 15);
                float v = fmaxf(acc[m][n][j], 0.f);
                Smem[row * 128 + (((colx >> 3) ^ (row & 7)) << 3) + (colx & 7)] =
                    (short)f2bf(v);
            }
        }
    }
    __syncthreads();
    #pragma unroll
    for (int i = 0; i < 8; ++i) {
        int c = i * 256 + tid;
        int r = c >> 4, c8 = c & 15;
        int grow = bm0 + r;
        if (grow < V_N)
            *(uint4*)&C[(size_t)grow * ldc + c8 * 8] =
                *(const uint4*)&Smem[r * 128 + (c8 ^ (r & 7)) * 8];
    }
}

// ---------------------------------------------------------------------------
// Neighbor sum: s[v] = sum_{u in adj(v)} x[u]  (bf16 io, fp32 accum).
// One 16-lane group per vertex, vertex = perm[g] (degree-sorted order ->
// co-scheduled vertices have near-equal degree -> no lockstep inflation).
// Per-vertex summation order unchanged -> results bit-identical to unsorted.
// ---------------------------------------------------------------------------
__global__ __launch_bounds__(256) void agg_sum_kernel(
    const short* __restrict__ x, const int* __restrict__ rowp,
    const int* __restrict__ col, const int* __restrict__ perm,
    short* __restrict__ s)
{
    int g  = (blockIdx.x * 256 + threadIdx.x) >> 4;
    int il = threadIdx.x & 15;
    if (g >= V_N) return;
    int v = perm[g];
    int st = rowp[v], en = rowp[v + 1];
    float a[8] = {0.f, 0.f, 0.f, 0.f, 0.f, 0.f, 0.f, 0.f};
    int p = st;
    for (; p + 4 <= en; p += 4) {
        int u0 = col[p], u1 = col[p + 1], u2 = col[p + 2], u3 = col[p + 3];
        uint4 q0 = *(const uint4*)(x + (size_t)u0 * 128 + il * 8);
        uint4 q1 = *(const uint4*)(x + (size_t)u1 * 128 + il * 8);
        uint4 q2 = *(const uint4*)(x + (size_t)u2 * 128 + il * 8);
        uint4 q3 = *(const uint4*)(x + (size_t)u3 * 128 + il * 8);
        acc8(a, q0); acc8(a, q1); acc8(a, q2); acc8(a, q3);
    }
    if (p + 2 <= en) {
        int u0 = col[p], u1 = col[p + 1];
        uint4 q0 = *(const uint4*)(x + (size_t)u0 * 128 + il * 8);
        uint4 q1 = *(const uint4*)(x + (size_t)u1 * 128 + il * 8);
        acc8(a, q0); acc8(a, q1);
        p += 2;
    }
    if (p < en) {
        uint4 q = *(const uint4*)(x + (size_t)col[p] * 128 + il * 8);
        acc8(a, q);
    }
    uint4 w;
    w.x = (unsigned)f2bf(a[0]) | ((unsigned)f2bf(a[1]) << 16);
    w.y = (unsigned)f2bf(a[2]) | ((unsigned)f2bf(a[3]) << 16);
    w.z = (unsigned)f2bf(a[4]) | ((unsigned)f2bf(a[5]) << 16);
    w.w = (unsigned)f2bf(a[6]) | ((unsigned)f2bf(a[7]) << 16);
    *(uint4*)(s + (size_t)v * 128 + il * 8) = w;
}

// ---------------------------------------------------------------------------
// GraphConv GEMM (in-place): X[v] = relu( [S[v]|X[v]] @ B^T + b0 + deg*b1
//   (+ L0: W0v.verts[v] + W1v.sv[v]) ),  K=256, N=128.
// VOUT (last layer): out[v] = relu_row @ voW^T + vob computed from acc
// registers in fp32 (shfl-reduce over the 16-lane col group + 2-contributor
// LDS atomicAdd across the wn wave pair); X is not written.
// ---------------------------------------------------------------------------
template<bool L0, bool VOUT>
__global__ __launch_bounds__(256) void gconv_mfma_kernel(
    short* __restrict__ X,                     // [V][128] bf16 (A and C)
    const short* __restrict__ S,               // [V][128] bf16
    const short* __restrict__ B,               // [128][256] bf16
    const float* __restrict__ b0, const float* __restrict__ b1,
    const int* __restrict__ deg,
    const float* __restrict__ verts,           // L0 only
    const float* __restrict__ sv,              // [V][4] f32, L0 only
    const float* __restrict__ Wv,              // [128][8] f32, L0 only
    const float* __restrict__ voW,             // [3][128] f32, VOUT only
    const float* __restrict__ vob,             // [3] f32, VOUT only
    float* __restrict__ out)                   // [V][3] f32, VOUT only
{
    __shared__ short Smem[128 * 128];
    short* As = Smem;
    short* Bs = Smem + 128 * 64;
    const int tid = threadIdx.x;
    const int bm0 = blockIdx.x * 128;
    const int wid = tid >> 6, lane = tid & 63;
    const int wm = wid >> 1, wn = wid & 1;
    const int srow = wid * 32 + (lane >> 3);
    const int sc   = lane & 7;

    f32x4 acc[4][4] = {};

    for (int it = 0; it < 4; ++it) {
        const short* Ap = (it < 2) ? S : X;
        const int k0 = (it & 1) * 64;
        __syncthreads();
        #pragma unroll
        for (int i = 0; i < 4; ++i) {
            int row = srow + i * 8;
            int g = (sc ^ (row & 7)) << 3;
            int grow = bm0 + row; if (grow >= V_N) grow = V_N - 1;
            gload_lds16(Ap + (size_t)grow * 128 + k0 + g, As + (wid * 32 + i * 8) * 64);
            gload_lds16(B + (size_t)row * 256 + it * 64 + g, Bs + (wid * 32 + i * 8) * 64);
        }
        __syncthreads();
        #pragma unroll
        for (int kk = 0; kk < 2; ++kk) {
            bf16x8 a[4], b[4];
            #pragma unroll
            for (int m = 0; m < 4; ++m) {
                int row = wm * 64 + m * 16 + (lane & 15);
                int e = (row * 64 + kk * 32 + (lane >> 4) * 8) ^ ((row & 7) << 3);
                a[m] = *(const bf16x8*)&As[e];
            }
            #pragma unroll
            for (int n = 0; n < 4; ++n) {
                int row = wn * 64 + n * 16 + (lane & 15);
                int e = (row * 64 + kk * 32 + (lane >> 4) * 8) ^ ((row & 7) << 3);
                b[n] = *(const bf16x8*)&Bs[e];
            }
            #pragma unroll
            for (int m = 0; m < 4; ++m)
                #pragma unroll
                for (int n = 0; n < 4; ++n)
                    acc[m][n] = __builtin_amdgcn_mfma_f32_16x16x32_bf16(
                        a[m], b[n], acc[m][n], 0, 0, 0);
        }
    }

    // bias / L0 weight preload (col-dependent)
    float bb0[4], bb1[4];
    float w0v[4][3], w1v[4][3];
    #pragma unroll
    for (int n = 0; n < 4; ++n) {
        int colx = wn * 64 + n * 16 + (lane & 15);
        bb0[n] = b0[colx]; bb1[n] = b1[colx];
        if (L0) {
            #pragma unroll
            for (int k = 0; k < 3; ++k) {
                w0v[n][k] = Wv[colx * 8 + k];
                w1v[n][k] = Wv[colx * 8 + 4 + k];
            }
        }
    }

    if constexpr (VOUT) {
        // ---- fused final projection, all fp32 from registers ----
        float wv0[4], wv1[4], wv2[4];
        #pragma unroll
        for (int n = 0; n < 4; ++n) {
            int colx = wn * 64 + n * 16 + (lane & 15);
            wv0[n] = voW[colx]; wv1[n] = voW[128 + colx]; wv2[n] = voW[256 + colx];
        }
        __syncthreads();                 // As/Bs reads complete; reuse Smem
        float* vsum = (float*)Smem;      // [128][4] f32
        for (int q = tid; q < 512; q += 256) vsum[q] = 0.f;
        __syncthreads();
        #pragma unroll
        for (int m = 0; m < 4; ++m) {
            #pragma unroll
            for (int j = 0; j < 4; ++j) {
                int row = wm * 64 + m * 16 + (lane >> 4) * 4 + j;
                int grow = bm0 + row; if (grow >= V_N) grow = V_N - 1;
                float dv = (float)deg[grow];
                float p0 = 0.f, p1 = 0.f, p2 = 0.f;
                #pragma unroll
                for (int n = 0; n < 4; ++n) {
                    float v = fmaxf(acc[m][n][j] + bb0[n] + dv * bb1[n], 0.f);
                    p0 += v * wv0[n]; p1 += v * wv1[n]; p2 += v * wv2[n];
                }
                #pragma unroll
                for (int off = 1; off < 16; off <<= 1) {
                    p0 += __shfl_xor(p0, off);
                    p1 += __shfl_xor(p1, off);
                    p2 += __shfl_xor(p2, off);
                }
                if ((lane & 15) == 0) {   // 2 contributors/row (wn pair):
                    atomicAdd(&vsum[row * 4 + 0], p0);   // 2-term fp add is
                    atomicAdd(&vsum[row * 4 + 1], p1);   // order-invariant
                    atomicAdd(&vsum[row * 4 + 2], p2);
                }
            }
        }
        __syncthreads();
        if (tid < 128) {
            int grow = bm0 + tid;
            if (grow < V_N) {
                out[3 * grow]     = vsum[tid * 4]     + vob[0];
                out[3 * grow + 1] = vsum[tid * 4 + 1] + vob[1];
                out[3 * grow + 2] = vsum[tid * 4 + 2] + vob[2];
            }
        }
        return;
    }

    __syncthreads();
    #pragma unroll
    for (int m = 0; m < 4; ++m) {
        #pragma unroll
        for (int j = 0; j < 4; ++j) {
            int row = wm * 64 + m * 16 + (lane >> 4) * 4 + j;
            int grow = bm0 + row; if (grow >= V_N) grow = V_N - 1;
            float dv = (float)deg[grow];
            float vx = 0.f, vy = 0.f, vz = 0.f;
            float4 s4 = {0.f, 0.f, 0.f, 0.f};
            if (L0) {
                vx = verts[3 * grow]; vy = verts[3 * grow + 1]; vz = verts[3 * grow + 2];
                s4 = *(const float4*)&sv[grow * 4];
            }
            #pragma unroll
            for (int n = 0; n < 4; ++n) {
                int colx = wn * 64 + n * 16 + (lane & 15);
                float v = acc[m][n][j] + bb0[n] + dv * bb1[n];
                if (L0)
                    v += w0v[n][0] * vx + w0v[n][1] * vy + w0v[n][2] * vz
                       + w1v[n][0] * s4.x + w1v[n][1] * s4.y + w1v[n][2] * s4.z;
                v = fmaxf(v, 0.f);
                Smem[row * 128 + (((colx >> 3) ^ (row & 7)) << 3) + (colx & 7)] =
                    (short)f2bf(v);
            }
        }
    }
    __syncthreads();
    #pragma unroll
    for (int i = 0; i < 8; ++i) {
        int c = i * 256 + tid;
        int r = c >> 4, c8 = c & 15;
        int grow = bm0 + r;
        if (grow < V_N)
            *(uint4*)&X[(size_t)grow * 128 + c8 * 8] =
                *(const uint4*)&Smem[r * 128 + (c8 ^ (r & 7)) * 8];
    }
}

// ------------------------- prep: weights + sv (one kernel) ----------------
__global__ __launch_bounds__(256) void prep_all_kernel(
    const float* __restrict__ bnW,
    const float* __restrict__ g0W0, const float* __restrict__ g0W1,
    const float* __restrict__ gW0,  const float* __restrict__ gW1,
    const float* __restrict__ verts,
    const int* __restrict__ rowp, const int* __restrict__ colv,
    short* __restrict__ bnWb, short* __restrict__ Wc,
    float* __restrict__ Wv, float* __restrict__ sv)
{
    int i = blockIdx.x * 256 + threadIdx.x;
    if (i < 128 * FEAT) bnWb[i] = (short)f2bf(bnW[i]);
    if (i < 8 * 128 * 256) {
        int l = i >> 15, r = (i >> 8) & 127, c = i & 255;
        float v;
        if (l == 0)
            v = (c < 128) ? g0W1[r * 131 + c] : g0W0[r * 131 + (c - 128)];
        else {
            int ll = l - 1;
            v = (c < 128) ? gW1[((size_t)ll * 128 + r) * 128 + c]
                          : gW0[((size_t)ll * 128 + r) * 128 + (c - 128)];
        }
        Wc[i] = (short)f2bf(v);
    }
    if (i < 128) {
        Wv[i * 8 + 0] = g0W0[i * 131 + 128];
        Wv[i * 8 + 1] = g0W0[i * 131 + 129];
        Wv[i * 8 + 2] = g0W0[i * 131 + 130];
        Wv[i * 8 + 3] = 0.f;
        Wv[i * 8 + 4] = g0W1[i * 131 + 128];
        Wv[i * 8 + 5] = g0W1[i * 131 + 129];
        Wv[i * 8 + 6] = g0W1[i * 131 + 130];
        Wv[i * 8 + 7] = 0.f;
    }
    if (i < V_N) {
        float sx = 0.f, sy = 0.f, sz = 0.f;
        int en = rowp[i + 1];
        for (int p = rowp[i]; p < en; ++p) {
            int u = colv[p];
            sx += verts[3 * u]; sy += verts[3 * u + 1]; sz += verts[3 * u + 2];
        }
        float4 o = {sx, sy, sz, 0.f};
        *(float4*)&sv[(size_t)i * 4] = o;
    }
}

// ------------------------- CSR construction -------------------------------
__global__ void deg_count_kernel(const int* __restrict__ edges, int* __restrict__ deg)
{
    int e = blockIdx.x * blockDim.x + threadIdx.x;
    if (e >= E_N) return;
    int i = edges[2 * e], j = edges[2 * e + 1];
    atomicAdd(&deg[i], 1);
    atomicAdd(&deg[j], 1);
}

__global__ __launch_bounds__(1024) void scan_block_kernel(
    const int* __restrict__ deg, int* __restrict__ excl, int* __restrict__ bsum)
{
    __shared__ int sdata[1024];
    int t = threadIdx.x;
    int base = blockIdx.x * 1024;
    int val = (base + t < V_N) ? deg[base + t] : 0;
    sdata[t] = val; __syncthreads();
    for (int off = 1; off < 1024; off <<= 1) {
        int tmp = (t >= off) ? sdata[t - off] : 0;
        __syncthreads();
        sdata[t] += tmp;
        __syncthreads();
    }
    if (base + t < V_N) excl[base + t] = sdata[t] - val;
    if (t == 1023) bsum[blockIdx.x] = sdata[1023];
}

__global__ __launch_bounds__(256) void scan_bsum_kernel(
    const int* __restrict__ bsum, int* __restrict__ boff)
{
    __shared__ int sdata[256];
    int t = threadIdx.x;
    int val = (t < NSCAN) ? bsum[t] : 0;
    sdata[t] = val; __syncthreads();
    for (int off = 1; off < 256; off <<= 1) {
        int tmp = (t >= off) ? sdata[t - off] : 0;
        __syncthreads();
        sdata[t] += tmp;
        __syncthreads();
    }
    if (t < NSCAN) boff[t] = sdata[t] - val;
    if (t == 255) boff[NSCAN] = sdata[255];
}

// also histograms degrees (64 bins) for the gather load-balance sort
__global__ void scan_add_kernel(const int* __restrict__ boff,
                                int* __restrict__ rowp, int* __restrict__ cur,
                                const int* __restrict__ deg, int* __restrict__ hist)
{
    int i = blockIdx.x * blockDim.x + threadIdx.x;
    if (i < V_N) {
        int r = rowp[i] + boff[i >> 10];
        rowp[i] = r;
        cur[i] = r;
        atomicAdd(&hist[min(deg[i], 63)], 1);
    } else if (i == V_N) {
        rowp[V_N] = boff[NSCAN];
    }
}

__global__ void fill_kernel(const int* __restrict__ edges,
                            int* __restrict__ cur, int* __restrict__ col)
{
    int e = blockIdx.x * blockDim.x + threadIdx.x;
    if (e >= E_N) return;
    int i = edges[2 * e], j = edges[2 * e + 1];
    col[atomicAdd(&cur[i], 1)] = j;
    col[atomicAdd(&cur[j], 1)] = i;
}

// exclusive scan of the 64-bin degree histogram -> bin cursors
__global__ void binscan_kernel(const int* __restrict__ hist, int* __restrict__ binptr)
{
    __shared__ int sdata[64];
    int t = threadIdx.x;   // 64 threads
    int val = hist[t];
    sdata[t] = val; __syncthreads();
    for (int off = 1; off < 64; off <<= 1) {
        int tmp = (t >= off) ? sdata[t - off] : 0;
        __syncthreads();
        sdata[t] += tmp;
        __syncthreads();
    }
    binptr[t] = sdata[t] - val;
}

// perm = vertices in (non-decreasing) degree order
__global__ void permfill_kernel(const int* __restrict__ deg,
                                int* __restrict__ binptr, int* __restrict__ perm)
{
    int v = blockIdx.x * 256 + threadIdx.x;
    if (v >= V_N) return;
    int b = min(deg[v], 63);
    perm[atomicAdd(&binptr[b], 1)] = v;
}

// ---------------------------------------------------------------------------
extern "C" void kernel_launch(void* const* d_in, const int* in_sizes, int n_in,
                              void* d_out, int out_size, void* d_ws, size_t ws_size,
                              hipStream_t stream)
{
    const float* img   = (const float*)d_in[0];
    const float* verts = (const float*)d_in[1];
    const int*   edges = (const int*)  d_in[2];
    const float* bnW   = (const float*)d_in[3];
    const float* bnb   = (const float*)d_in[4];
    const float* g0W0  = (const float*)d_in[5];
    const float* g0b0  = (const float*)d_in[6];
    const float* g0W1  = (const float*)d_in[7];
    const float* g0b1  = (const float*)d_in[8];
    const float* gW0   = (const float*)d_in[9];
    const float* gb0   = (const float*)d_in[10];
    const float* gW1   = (const float*)d_in[11];
    const float* gb1   = (const float*)d_in[12];
    const float* voW   = (const float*)d_in[13];
    const float* vob   = (const float*)d_in[14];
    float* out = (float*)d_out;

    // workspace layout (16B-aligned segments)
    short* xa   = (short*)d_ws;                       // V*128 bf16
    short* sb   = xa   + (size_t)V_N * 128;           // V*128 bf16
    short* bnWb = sb   + (size_t)V_N * 128;           // 128*960
    short* Wc   = bnWb + 128 * FEAT;                  // 8*128*256
    float* Wv   = (float*)(Wc + 8 * 128 * 256);       // 128*8
    float* sv   = Wv   + 128 * 8;                     // V*4
    int*   deg  = (int*)(sv + (size_t)V_N * 4);       // V
    int*   hist = deg  + V_N;                         // 64 (zeroed with deg)
    int*   rowp = hist + 64;                          // V+1
    int*   cur  = rowp + V_N + 1;                     // V
    int*   bsum = cur  + V_N;                         // 256
    int*   boff = bsum + 256;                         // NSCAN+1
    int*   binp = boff + 257;                         // 64
    int*   perm = binp + 64;                          // V
    int*   col  = perm + V_N;                         // 2E

    // ---- CSR build + degree-sort perm ----
    hipMemsetAsync(deg, 0, (V_N + 64) * sizeof(int), stream);
    deg_count_kernel<<<(E_N + 255) / 256, 256, 0, stream>>>(edges, deg);
    scan_block_kernel<<<NSCAN, 1024, 0, stream>>>(deg, rowp, bsum);
    scan_bsum_kernel<<<1, 256, 0, stream>>>(bsum, boff);
    scan_add_kernel<<<(V_N + 256) / 256, 256, 0, stream>>>(boff, rowp, cur, deg, hist);
    fill_kernel<<<(E_N + 255) / 256, 256, 0, stream>>>(edges, cur, col);
    binscan_kernel<<<1, 64, 0, stream>>>(hist, binp);
    permfill_kernel<<<(V_N + 255) / 256, 256, 0, stream>>>(deg, binp, perm);

    // ---- prep (weights + sv; after CSR) ----
    prep_all_kernel<<<(8 * 128 * 256 + 255) / 256, 256, 0, stream>>>(
        bnW, g0W0, g0W1, gW0, gW1, verts, rowp, col, bnWb, Wc, Wv, sv);

    const int MB = (V_N + 127) / 128;          // 1563
    const int AGGB = (V_N * 16 + 255) / 256;   // 12500

    // ---- backbone: img(fp32,K=960) @ bnW^T -> xa (relu) ----
    backbone_mfma_kernel<15><<<MB, 256, 0, stream>>>(img, FEAT, bnWb, FEAT, bnb, xa, 128);

    // ---- layer 0 (verts via epilogue) ----
    agg_sum_kernel<<<AGGB, 256, 0, stream>>>(xa, rowp, col, perm, sb);
    gconv_mfma_kernel<true, false><<<MB, 256, 0, stream>>>(
        xa, sb, Wc, g0b0, g0b1, deg, verts, sv, Wv, nullptr, nullptr, nullptr);

    // ---- layers 1..6 (in-place on xa) ----
    for (int l = 1; l < NREST; ++l) {
        agg_sum_kernel<<<AGGB, 256, 0, stream>>>(xa, rowp, col, perm, sb);
        gconv_mfma_kernel<false, false><<<MB, 256, 0, stream>>>(
            xa, sb, Wc + (size_t)l * 128 * 256,
            gb0 + (size_t)(l - 1) * 128, gb1 + (size_t)(l - 1) * 128,
            deg, nullptr, nullptr, nullptr, nullptr, nullptr, nullptr);
    }

    // ---- layer 7 + fused final projection (fp32 register path) ----
    agg_sum_kernel<<<AGGB, 256, 0, stream>>>(xa, rowp, col, perm, sb);
    gconv_mfma_kernel<false, true><<<MB, 256, 0, stream>>>(
        xa, sb, Wc + (size_t)NREST * 128 * 256,
        gb0 + (size_t)(NREST - 1) * 128, gb1 + (size_t)(NREST - 1) * 128,
        deg, nullptr, nullptr, nullptr, voW, vob, out);
}

// Round 10
// 1099.205 us; speedup vs baseline: 2.3134x; 2.3134x over previous
//
#include <hip/hip_runtime.h>

#define V_N   200000
#define E_N   600000
#define FEAT  960
#define HDIM  128
#define NREST 7
#define NSCAN 196   // ceil(V_N/1024)
#define NB    782   // ceil((V_N+1)/256)

typedef __attribute__((ext_vector_type(8))) short bf16x8;
typedef __attribute__((ext_vector_type(4))) float f32x4;

__device__ __forceinline__ unsigned short f2bf(float f) {
    unsigned u = __builtin_bit_cast(unsigned, f);
    unsigned r = (u + 0x7FFFu + ((u >> 16) & 1u)) >> 16;
    return (unsigned short)r;
}
__device__ __forceinline__ float bf2f(unsigned h) {
    unsigned u = h << 16;
    return __builtin_bit_cast(float, u);
}

// async global->LDS, 16B per lane; LDS dest wave-uniform base + lane*16.
__device__ __forceinline__ void gload_lds16(const void* g, void* l) {
    __builtin_amdgcn_global_load_lds(
        (const __attribute__((address_space(1))) void*)g,
        (__attribute__((address_space(3))) void*)l, 16, 0, 0);
}

__device__ __forceinline__ void acc8(float* a, uint4 q) {
    a[0] += bf2f(q.x & 0xffffu); a[1] += bf2f(q.x >> 16);
    a[2] += bf2f(q.y & 0xffffu); a[3] += bf2f(q.y >> 16);
    a[4] += bf2f(q.z & 0xffffu); a[5] += bf2f(q.z >> 16);
    a[6] += bf2f(q.w & 0xffffu); a[7] += bf2f(q.w >> 16);
}

// ---------------------------------------------------------------------------
// Backbone MFMA GEMM: C = relu(A(fp32) @ B^T + bias), BM=BN=128, BK=64.
// ---------------------------------------------------------------------------
template<int KT>
__global__ __launch_bounds__(256) void backbone_mfma_kernel(
    const float* __restrict__ A, int lda,
    const short* __restrict__ B, int ldb,
    const float* __restrict__ bias,
    short* __restrict__ C, int ldc)
{
    __shared__ short Smem[128 * 128];
    short* As = Smem;
    short* Bs = Smem + 128 * 64;
    const int tid = threadIdx.x;
    const int bm0 = blockIdx.x * 128;
    const int wid = tid >> 6, lane = tid & 63;
    const int wm = wid >> 1, wn = wid & 1;
    const int srow = wid * 32 + (lane >> 3);
    const int sc   = lane & 7;

    f32x4 acc[4][4];
    #pragma unroll
    for (int n = 0; n < 4; ++n) {
        float bv = bias[wn * 64 + n * 16 + (lane & 15)];
        #pragma unroll
        for (int m = 0; m < 4; ++m)
            acc[m][n] = (f32x4){bv, bv, bv, bv};
    }

    for (int it = 0; it < KT; ++it) {
        const int k0 = it * 64;
        __syncthreads();
        #pragma unroll
        for (int i = 0; i < 8; ++i) {
            int c = i * 256 + tid;
            int row = c >> 4, c4 = c & 15;
            int grow = bm0 + row; if (grow >= V_N) grow = V_N - 1;
            float4 t = *(const float4*)(A + (size_t)grow * lda + k0 + c4 * 4);
            unsigned lo = (unsigned)f2bf(t.x) | ((unsigned)f2bf(t.y) << 16);
            unsigned hi = (unsigned)f2bf(t.z) | ((unsigned)f2bf(t.w) << 16);
            int e = (row * 64 + c4 * 4) ^ ((row & 7) << 3);
            *(uint2*)&As[e] = make_uint2(lo, hi);
        }
        #pragma unroll
        for (int i = 0; i < 4; ++i) {
            int row = srow + i * 8;
            int g = (sc ^ (row & 7)) << 3;
            gload_lds16(B + (size_t)row * ldb + k0 + g, Bs + (wid * 32 + i * 8) * 64);
        }
        __syncthreads();
        #pragma unroll
        for (int kk = 0; kk < 2; ++kk) {
            bf16x8 a[4], b[4];
            #pragma unroll
            for (int m = 0; m < 4; ++m) {
                int row = wm * 64 + m * 16 + (lane & 15);
                int e = (row * 64 + kk * 32 + (lane >> 4) * 8) ^ ((row & 7) << 3);
                a[m] = *(const bf16x8*)&As[e];
            }
            #pragma unroll
            for (int n = 0; n < 4; ++n) {
                int row = wn * 64 + n * 16 + (lane & 15);
                int e = (row * 64 + kk * 32 + (lane >> 4) * 8) ^ ((row & 7) << 3);
                b[n] = *(const bf16x8*)&Bs[e];
            }
            #pragma unroll
            for (int m = 0; m < 4; ++m)
                #pragma unroll
                for (int n = 0; n < 4; ++n)
                    acc[m][n] = __builtin_amdgcn_mfma_f32_16x16x32_bf16(
                        a[m], b[n], acc[m][n], 0, 0, 0);
        }
    }

    __syncthreads();
    #pragma unroll
    for (int m = 0; m < 4; ++m) {
        #pragma unroll
        for (int j = 0; j < 4; ++j) {
            int row = wm * 64 + m * 16 + (lane >> 4) * 4 + j;
            #pragma unroll
            for (int n = 0; n < 4; ++n) {
                int colx = wn * 64 + n * 16 + (lane & 15);
                float v = fmaxf(acc[m][n][j], 0.f);
                Smem[row * 128 + (((colx >> 3) ^ (row & 7)) << 3) + (colx & 7)] =
                    (short)f2bf(v);
            }
        }
    }
    __syncthreads();
    #pragma unroll
    for (int i = 0; i < 8; ++i) {
        int c = i * 256 + tid;
        int r = c >> 4, c8 = c & 15;
        int grow = bm0 + r;
        if (grow < V_N)
            *(uint4*)&C[(size_t)grow * ldc + c8 * 8] =
                *(const uint4*)&Smem[r * 128 + (c8 ^ (r & 7)) * 8];
    }
}

// ---------------------------------------------------------------------------
// Neighbor sum: s[v] = sum_{u in adj(v)} x[u]  (bf16 io, fp32 accum).
// One 16-lane group per vertex, vertex = perm[g] (degree-sorted order).
// Per-vertex summation order unchanged -> results bit-identical to unsorted.
// ---------------------------------------------------------------------------
__global__ __launch_bounds__(256) void agg_sum_kernel(
    const short* __restrict__ x, const int* __restrict__ rowp,
    const int* __restrict__ col, const int* __restrict__ perm,
    short* __restrict__ s)
{
    int g  = (blockIdx.x * 256 + threadIdx.x) >> 4;
    int il = threadIdx.x & 15;
    if (g >= V_N) return;
    int v = perm[g];
    int st = rowp[v], en = rowp[v + 1];
    float a[8] = {0.f, 0.f, 0.f, 0.f, 0.f, 0.f, 0.f, 0.f};
    int p = st;
    for (; p + 4 <= en; p += 4) {
        int u0 = col[p], u1 = col[p + 1], u2 = col[p + 2], u3 = col[p + 3];
        uint4 q0 = *(const uint4*)(x + (size_t)u0 * 128 + il * 8);
        uint4 q1 = *(const uint4*)(x + (size_t)u1 * 128 + il * 8);
        uint4 q2 = *(const uint4*)(x + (size_t)u2 * 128 + il * 8);
        uint4 q3 = *(const uint4*)(x + (size_t)u3 * 128 + il * 8);
        acc8(a, q0); acc8(a, q1); acc8(a, q2); acc8(a, q3);
    }
    if (p + 2 <= en) {
        int u0 = col[p], u1 = col[p + 1];
        uint4 q0 = *(const uint4*)(x + (size_t)u0 * 128 + il * 8);
        uint4 q1 = *(const uint4*)(x + (size_t)u1 * 128 + il * 8);
        acc8(a, q0); acc8(a, q1);
        p += 2;
    }
    if (p < en) {
        uint4 q = *(const uint4*)(x + (size_t)col[p] * 128 + il * 8);
        acc8(a, q);
    }
    uint4 w;
    w.x = (unsigned)f2bf(a[0]) | ((unsigned)f2bf(a[1]) << 16);
    w.y = (unsigned)f2bf(a[2]) | ((unsigned)f2bf(a[3]) << 16);
    w.z = (unsigned)f2bf(a[4]) | ((unsigned)f2bf(a[5]) << 16);
    w.w = (unsigned)f2bf(a[6]) | ((unsigned)f2bf(a[7]) << 16);
    *(uint4*)(s + (size_t)v * 128 + il * 8) = w;
}

// ---------------------------------------------------------------------------
// GraphConv GEMM (in-place): X[v] = relu( [S[v]|X[v]] @ B^T + b0 + deg*b1
//   (+ L0: W0v.verts[v] + W1v.sv[v]) ),  K=256, N=128.
// VOUT (last layer): out[v] from acc registers in fp32 (validated round 9).
// ---------------------------------------------------------------------------
template<bool L0, bool VOUT>
__global__ __launch_bounds__(256) void gconv_mfma_kernel(
    short* __restrict__ X,                     // [V][128] bf16 (A and C)
    const short* __restrict__ S,               // [V][128] bf16
    const short* __restrict__ B,               // [128][256] bf16
    const float* __restrict__ b0, const float* __restrict__ b1,
    const int* __restrict__ deg,
    const float* __restrict__ verts,           // L0 only
    const float* __restrict__ sv,              // [V][4] f32, L0 only
    const float* __restrict__ Wv,              // [128][8] f32, L0 only
    const float* __restrict__ voW,             // [3][128] f32, VOUT only
    const float* __restrict__ vob,             // [3] f32, VOUT only
    float* __restrict__ out)                   // [V][3] f32, VOUT only
{
    __shared__ short Smem[128 * 128];
    short* As = Smem;
    short* Bs = Smem + 128 * 64;
    const int tid = threadIdx.x;
    const int bm0 = blockIdx.x * 128;
    const int wid = tid >> 6, lane = tid & 63;
    const int wm = wid >> 1, wn = wid & 1;
    const int srow = wid * 32 + (lane >> 3);
    const int sc   = lane & 7;

    f32x4 acc[4][4] = {};

    for (int it = 0; it < 4; ++it) {
        const short* Ap = (it < 2) ? S : X;
        const int k0 = (it & 1) * 64;
        __syncthreads();
        #pragma unroll
        for (int i = 0; i < 4; ++i) {
            int row = srow + i * 8;
            int g = (sc ^ (row & 7)) << 3;
            int grow = bm0 + row; if (grow >= V_N) grow = V_N - 1;
            gload_lds16(Ap + (size_t)grow * 128 + k0 + g, As + (wid * 32 + i * 8) * 64);
            gload_lds16(B + (size_t)row * 256 + it * 64 + g, Bs + (wid * 32 + i * 8) * 64);
        }
        __syncthreads();
        #pragma unroll
        for (int kk = 0; kk < 2; ++kk) {
            bf16x8 a[4], b[4];
            #pragma unroll
            for (int m = 0; m < 4; ++m) {
                int row = wm * 64 + m * 16 + (lane & 15);
                int e = (row * 64 + kk * 32 + (lane >> 4) * 8) ^ ((row & 7) << 3);
                a[m] = *(const bf16x8*)&As[e];
            }
            #pragma unroll
            for (int n = 0; n < 4; ++n) {
                int row = wn * 64 + n * 16 + (lane & 15);
                int e = (row * 64 + kk * 32 + (lane >> 4) * 8) ^ ((row & 7) << 3);
                b[n] = *(const bf16x8*)&Bs[e];
            }
            #pragma unroll
            for (int m = 0; m < 4; ++m)
                #pragma unroll
                for (int n = 0; n < 4; ++n)
                    acc[m][n] = __builtin_amdgcn_mfma_f32_16x16x32_bf16(
                        a[m], b[n], acc[m][n], 0, 0, 0);
        }
    }

    // bias / L0 weight preload (col-dependent)
    float bb0[4], bb1[4];
    float w0v[4][3], w1v[4][3];
    #pragma unroll
    for (int n = 0; n < 4; ++n) {
        int colx = wn * 64 + n * 16 + (lane & 15);
        bb0[n] = b0[colx]; bb1[n] = b1[colx];
        if (L0) {
            #pragma unroll
            for (int k = 0; k < 3; ++k) {
                w0v[n][k] = Wv[colx * 8 + k];
                w1v[n][k] = Wv[colx * 8 + 4 + k];
            }
        }
    }

    if constexpr (VOUT) {
        // ---- fused final projection, all fp32 from registers ----
        float wv0[4], wv1[4], wv2[4];
        #pragma unroll
        for (int n = 0; n < 4; ++n) {
            int colx = wn * 64 + n * 16 + (lane & 15);
            wv0[n] = voW[colx]; wv1[n] = voW[128 + colx]; wv2[n] = voW[256 + colx];
        }
        __syncthreads();                 // As/Bs reads complete; reuse Smem
        float* vsum = (float*)Smem;      // [128][4] f32
        for (int q = tid; q < 512; q += 256) vsum[q] = 0.f;
        __syncthreads();
        #pragma unroll
        for (int m = 0; m < 4; ++m) {
            #pragma unroll
            for (int j = 0; j < 4; ++j) {
                int row = wm * 64 + m * 16 + (lane >> 4) * 4 + j;
                int grow = bm0 + row; if (grow >= V_N) grow = V_N - 1;
                float dv = (float)deg[grow];
                float p0 = 0.f, p1 = 0.f, p2 = 0.f;
                #pragma unroll
                for (int n = 0; n < 4; ++n) {
                    float v = fmaxf(acc[m][n][j] + bb0[n] + dv * bb1[n], 0.f);
                    p0 += v * wv0[n]; p1 += v * wv1[n]; p2 += v * wv2[n];
                }
                #pragma unroll
                for (int off = 1; off < 16; off <<= 1) {
                    p0 += __shfl_xor(p0, off);
                    p1 += __shfl_xor(p1, off);
                    p2 += __shfl_xor(p2, off);
                }
                if ((lane & 15) == 0) {   // 2 contributors/row (wn pair)
                    atomicAdd(&vsum[row * 4 + 0], p0);
                    atomicAdd(&vsum[row * 4 + 1], p1);
                    atomicAdd(&vsum[row * 4 + 2], p2);
                }
            }
        }
        __syncthreads();
        if (tid < 128) {
            int grow = bm0 + tid;
            if (grow < V_N) {
                out[3 * grow]     = vsum[tid * 4]     + vob[0];
                out[3 * grow + 1] = vsum[tid * 4 + 1] + vob[1];
                out[3 * grow + 2] = vsum[tid * 4 + 2] + vob[2];
            }
        }
        return;
    }

    __syncthreads();
    #pragma unroll
    for (int m = 0; m < 4; ++m) {
        #pragma unroll
        for (int j = 0; j < 4; ++j) {
            int row = wm * 64 + m * 16 + (lane >> 4) * 4 + j;
            int grow = bm0 + row; if (grow >= V_N) grow = V_N - 1;
            float dv = (float)deg[grow];
            float vx = 0.f, vy = 0.f, vz = 0.f;
            float4 s4 = {0.f, 0.f, 0.f, 0.f};
            if (L0) {
                vx = verts[3 * grow]; vy = verts[3 * grow + 1]; vz = verts[3 * grow + 2];
                s4 = *(const float4*)&sv[grow * 4];
            }
            #pragma unroll
            for (int n = 0; n < 4; ++n) {
                int colx = wn * 64 + n * 16 + (lane & 15);
                float v = acc[m][n][j] + bb0[n] + dv * bb1[n];
                if (L0)
                    v += w0v[n][0] * vx + w0v[n][1] * vy + w0v[n][2] * vz
                       + w1v[n][0] * s4.x + w1v[n][1] * s4.y + w1v[n][2] * s4.z;
                v = fmaxf(v, 0.f);
                Smem[row * 128 + (((colx >> 3) ^ (row & 7)) << 3) + (colx & 7)] =
                    (short)f2bf(v);
            }
        }
    }
    __syncthreads();
    #pragma unroll
    for (int i = 0; i < 8; ++i) {
        int c = i * 256 + tid;
        int r = c >> 4, c8 = c & 15;
        int grow = bm0 + r;
        if (grow < V_N)
            *(uint4*)&X[(size_t)grow * 128 + c8 * 8] =
                *(const uint4*)&Smem[r * 128 + (c8 ^ (r & 7)) * 8];
    }
}

// ------------------------- prep: weights + sv (one kernel) ----------------
__global__ __launch_bounds__(256) void prep_all_kernel(
    const float* __restrict__ bnW,
    const float* __restrict__ g0W0, const float* __restrict__ g0W1,
    const float* __restrict__ gW0,  const float* __restrict__ gW1,
    const float* __restrict__ verts,
    const int* __restrict__ rowp, const int* __restrict__ colv,
    short* __restrict__ bnWb, short* __restrict__ Wc,
    float* __restrict__ Wv, float* __restrict__ sv)
{
    int i = blockIdx.x * 256 + threadIdx.x;
    if (i < 128 * FEAT) bnWb[i] = (short)f2bf(bnW[i]);
    if (i < 8 * 128 * 256) {
        int l = i >> 15, r = (i >> 8) & 127, c = i & 255;
        float v;
        if (l == 0)
            v = (c < 128) ? g0W1[r * 131 + c] : g0W0[r * 131 + (c - 128)];
        else {
            int ll = l - 1;
            v = (c < 128) ? gW1[((size_t)ll * 128 + r) * 128 + c]
                          : gW0[((size_t)ll * 128 + r) * 128 + (c - 128)];
        }
        Wc[i] = (short)f2bf(v);
    }
    if (i < 128) {
        Wv[i * 8 + 0] = g0W0[i * 131 + 128];
        Wv[i * 8 + 1] = g0W0[i * 131 + 129];
        Wv[i * 8 + 2] = g0W0[i * 131 + 130];
        Wv[i * 8 + 3] = 0.f;
        Wv[i * 8 + 4] = g0W1[i * 131 + 128];
        Wv[i * 8 + 5] = g0W1[i * 131 + 129];
        Wv[i * 8 + 6] = g0W1[i * 131 + 130];
        Wv[i * 8 + 7] = 0.f;
    }
    if (i < V_N) {
        float sx = 0.f, sy = 0.f, sz = 0.f;
        int en = rowp[i + 1];
        for (int p = rowp[i]; p < en; ++p) {
            int u = colv[p];
            sx += verts[3 * u]; sy += verts[3 * u + 1]; sz += verts[3 * u + 2];
        }
        float4 o = {sx, sy, sz, 0.f};
        *(float4*)&sv[(size_t)i * 4] = o;
    }
}

// ------------------------- CSR construction -------------------------------
__global__ void deg_count_kernel(const int* __restrict__ edges, int* __restrict__ deg)
{
    int e = blockIdx.x * blockDim.x + threadIdx.x;
    if (e >= E_N) return;
    int i = edges[2 * e], j = edges[2 * e + 1];
    atomicAdd(&deg[i], 1);
    atomicAdd(&deg[j], 1);
}

__global__ __launch_bounds__(1024) void scan_block_kernel(
    const int* __restrict__ deg, int* __restrict__ excl, int* __restrict__ bsum)
{
    __shared__ int sdata[1024];
    int t = threadIdx.x;
    int base = blockIdx.x * 1024;
    int val = (base + t < V_N) ? deg[base + t] : 0;
    sdata[t] = val; __syncthreads();
    for (int off = 1; off < 1024; off <<= 1) {
        int tmp = (t >= off) ? sdata[t - off] : 0;
        __syncthreads();
        sdata[t] += tmp;
        __syncthreads();
    }
    if (base + t < V_N) excl[base + t] = sdata[t] - val;
    if (t == 1023) bsum[blockIdx.x] = sdata[1023];
}

__global__ __launch_bounds__(256) void scan_bsum_kernel(
    const int* __restrict__ bsum, int* __restrict__ boff)
{
    __shared__ int sdata[256];
    int t = threadIdx.x;
    int val = (t < NSCAN) ? bsum[t] : 0;
    sdata[t] = val; __syncthreads();
    for (int off = 1; off < 256; off <<= 1) {
        int tmp = (t >= off) ? sdata[t - off] : 0;
        __syncthreads();
        sdata[t] += tmp;
        __syncthreads();
    }
    if (t < NSCAN) boff[t] = sdata[t] - val;
    if (t == 255) boff[NSCAN] = sdata[255];
}

// finalize rowp/cur + per-block degree histogram (LDS, no global hotspot)
__global__ __launch_bounds__(256) void scan_add_kernel(
    const int* __restrict__ boff, int* __restrict__ rowp, int* __restrict__ cur,
    const int* __restrict__ deg, int* __restrict__ bhist)
{
    __shared__ int lh[64];
    int t = threadIdx.x;
    if (t < 64) lh[t] = 0;
    __syncthreads();
    int i = blockIdx.x * 256 + t;
    if (i < V_N) {
        int r = rowp[i] + boff[i >> 10];
        rowp[i] = r;
        cur[i] = r;
        atomicAdd(&lh[min(deg[i], 63)], 1);
    } else if (i == V_N) {
        rowp[V_N] = boff[NSCAN];
    }
    __syncthreads();
    if (t < 64) bhist[blockIdx.x * 64 + t] = lh[t];
}

__global__ void fill_kernel(const int* __restrict__ edges,
                            int* __restrict__ cur, int* __restrict__ col)
{
    int e = blockIdx.x * blockDim.x + threadIdx.x;
    if (e >= E_N) return;
    int i = edges[2 * e], j = edges[2 * e + 1];
    col[atomicAdd(&cur[i], 1)] = j;
    col[atomicAdd(&cur[j], 1)] = i;
}

// per-bin running scan over per-block hists -> blockpref; scan totals -> binstart
__global__ __launch_bounds__(64) void binscan_kernel(
    const int* __restrict__ bhist,
    int* __restrict__ blockpref, int* __restrict__ binstart)
{
    __shared__ int sdata[64];
    int t = threadIdx.x;   // 64 threads, one per bin
    int running = 0;
    int b = 0;
    for (; b + 8 <= NB; b += 8) {
        int v[8];
        #pragma unroll
        for (int k = 0; k < 8; ++k) v[k] = bhist[(b + k) * 64 + t];
        #pragma unroll
        for (int k = 0; k < 8; ++k) {
            blockpref[(b + k) * 64 + t] = running;
            running += v[k];
        }
    }
    for (; b < NB; ++b) {
        blockpref[b * 64 + t] = running;
        running += bhist[b * 64 + t];
    }
    int val = running;
    sdata[t] = val; __syncthreads();
    for (int off = 1; off < 64; off <<= 1) {
        int tmp = (t >= off) ? sdata[t - off] : 0;
        __syncthreads();
        sdata[t] += tmp;
        __syncthreads();
    }
    binstart[t] = sdata[t] - val;
}

// perm via two-level counting sort (LDS-local ranks; no global hotspot)
__global__ __launch_bounds__(256) void permfill_kernel(
    const int* __restrict__ deg, const int* __restrict__ blockpref,
    const int* __restrict__ binstart, int* __restrict__ perm)
{
    __shared__ int lcur[64];
    int t = threadIdx.x;
    if (t < 64) lcur[t] = 0;
    __syncthreads();
    int v = blockIdx.x * 256 + t;
    if (v < V_N) {
        int b = min(deg[v], 63);
        int lrank = atomicAdd(&lcur[b], 1);
        perm[binstart[b] + blockpref[blockIdx.x * 64 + b] + lrank] = v;
    }
}

// ---------------------------------------------------------------------------
extern "C" void kernel_launch(void* const* d_in, const int* in_sizes, int n_in,
                              void* d_out, int out_size, void* d_ws, size_t ws_size,
                              hipStream_t stream)
{
    const float* img   = (const float*)d_in[0];
    const float* verts = (const float*)d_in[1];
    const int*   edges = (const int*)  d_in[2];
    const float* bnW   = (const float*)d_in[3];
    const float* bnb   = (const float*)d_in[4];
    const float* g0W0  = (const float*)d_in[5];
    const float* g0b0  = (const float*)d_in[6];
    const float* g0W1  = (const float*)d_in[7];
    const float* g0b1  = (const float*)d_in[8];
    const float* gW0   = (const float*)d_in[9];
    const float* gb0   = (const float*)d_in[10];
    const float* gW1   = (const float*)d_in[11];
    const float* gb1   = (const float*)d_in[12];
    const float* voW   = (const float*)d_in[13];
    const float* vob   = (const float*)d_in[14];
    float* out = (float*)d_out;

    // workspace layout (16B-aligned segments)
    short* xa    = (short*)d_ws;                      // V*128 bf16
    short* sb    = xa   + (size_t)V_N * 128;          // V*128 bf16
    short* bnWb  = sb   + (size_t)V_N * 128;          // 128*960
    short* Wc    = bnWb + 128 * FEAT;                 // 8*128*256
    float* Wv    = (float*)(Wc + 8 * 128 * 256);      // 128*8
    float* sv    = Wv   + 128 * 8;                    // V*4
    int*   deg   = (int*)(sv + (size_t)V_N * 4);      // V
    int*   rowp  = deg  + V_N;                        // V+1
    int*   cur   = rowp + V_N + 1;                    // V
    int*   bsum  = cur  + V_N;                        // 256
    int*   boff  = bsum + 256;                        // NSCAN+1
    int*   bhist = boff + 257;                        // NB*64
    int*   bpref = bhist + NB * 64;                   // NB*64
    int*   binst = bpref + NB * 64;                   // 64
    int*   perm  = binst + 64;                        // V
    int*   col   = perm + V_N;                        // 2E

    // ---- CSR build + degree-sort perm (two-level counting sort) ----
    hipMemsetAsync(deg, 0, V_N * sizeof(int), stream);
    deg_count_kernel<<<(E_N + 255) / 256, 256, 0, stream>>>(edges, deg);
    scan_block_kernel<<<NSCAN, 1024, 0, stream>>>(deg, rowp, bsum);
    scan_bsum_kernel<<<1, 256, 0, stream>>>(bsum, boff);
    scan_add_kernel<<<NB, 256, 0, stream>>>(boff, rowp, cur, deg, bhist);
    fill_kernel<<<(E_N + 255) / 256, 256, 0, stream>>>(edges, cur, col);
    binscan_kernel<<<1, 64, 0, stream>>>(bhist, bpref, binst);
    permfill_kernel<<<NB, 256, 0, stream>>>(deg, bpref, binst, perm);

    // ---- prep (weights + sv; after CSR) ----
    prep_all_kernel<<<(8 * 128 * 256 + 255) / 256, 256, 0, stream>>>(
        bnW, g0W0, g0W1, gW0, gW1, verts, rowp, col, bnWb, Wc, Wv, sv);

    const int MB = (V_N + 127) / 128;          // 1563
    const int AGGB = (V_N * 16 + 255) / 256;   // 12500

    // ---- backbone: img(fp32,K=960) @ bnW^T -> xa (relu) ----
    backbone_mfma_kernel<15><<<MB, 256, 0, stream>>>(img, FEAT, bnWb, FEAT, bnb, xa, 128);

    // ---- layer 0 (verts via epilogue) ----
    agg_sum_kernel<<<AGGB, 256, 0, stream>>>(xa, rowp, col, perm, sb);
    gconv_mfma_kernel<true, false><<<MB, 256, 0, stream>>>(
        xa, sb, Wc, g0b0, g0b1, deg, verts, sv, Wv, nullptr, nullptr, nullptr);

    // ---- layers 1..6 (in-place on xa) ----
    for (int l = 1; l < NREST; ++l) {
        agg_sum_kernel<<<AGGB, 256, 0, stream>>>(xa, rowp, col, perm, sb);
        gconv_mfma_kernel<false, false><<<MB, 256, 0, stream>>>(
            xa, sb, Wc + (size_t)l * 128 * 256,
            gb0 + (size_t)(l - 1) * 128, gb1 + (size_t)(l - 1) * 128,
            deg, nullptr, nullptr, nullptr, nullptr, nullptr, nullptr);
    }

    // ---- layer 7 + fused final projection (fp32 register path) ----
    agg_sum_kernel<<<AGGB, 256, 0, stream>>>(xa, rowp, col, perm, sb);
    gconv_mfma_kernel<false, true><<<MB, 256, 0, stream>>>(
        xa, sb, Wc + (size_t)NREST * 128 * 256,
        gb0 + (size_t)(NREST - 1) * 128, gb1 + (size_t)(NREST - 1) * 128,
        deg, nullptr, nullptr, nullptr, voW, vob, out);
}

// Round 11
// 1027.548 us; speedup vs baseline: 2.4747x; 1.0697x over previous
//
#include <hip/hip_runtime.h>

#define V_N   200000
#define E_N   600000
#define FEAT  960
#define HDIM  128
#define NREST 7
#define NSCAN 196   // ceil(V_N/1024)

typedef __attribute__((ext_vector_type(8))) short bf16x8;
typedef __attribute__((ext_vector_type(4))) float f32x4;

__device__ __forceinline__ unsigned short f2bf(float f) {
    unsigned u = __builtin_bit_cast(unsigned, f);
    unsigned r = (u + 0x7FFFu + ((u >> 16) & 1u)) >> 16;
    return (unsigned short)r;
}
__device__ __forceinline__ float bf2f(unsigned h) {
    unsigned u = h << 16;
    return __builtin_bit_cast(float, u);
}

// async global->LDS, 16B per lane; LDS dest wave-uniform base + lane*16.
__device__ __forceinline__ void gload_lds16(const void* g, void* l) {
    __builtin_amdgcn_global_load_lds(
        (const __attribute__((address_space(1))) void*)g,
        (__attribute__((address_space(3))) void*)l, 16, 0, 0);
}

__device__ __forceinline__ void acc8(float* a, uint4 q) {
    a[0] += bf2f(q.x & 0xffffu); a[1] += bf2f(q.x >> 16);
    a[2] += bf2f(q.y & 0xffffu); a[3] += bf2f(q.y >> 16);
    a[4] += bf2f(q.z & 0xffffu); a[5] += bf2f(q.z >> 16);
    a[6] += bf2f(q.w & 0xffffu); a[7] += bf2f(q.w >> 16);
}

// ---------------------------------------------------------------------------
// Backbone MFMA GEMM: C = relu(A(fp32) @ B^T + bias), BM=BN=128, BK=64.
// ---------------------------------------------------------------------------
template<int KT>
__global__ __launch_bounds__(256) void backbone_mfma_kernel(
    const float* __restrict__ A, int lda,
    const short* __restrict__ B, int ldb,
    const float* __restrict__ bias,
    short* __restrict__ C, int ldc)
{
    __shared__ short Smem[128 * 128];
    short* As = Smem;
    short* Bs = Smem + 128 * 64;
    const int tid = threadIdx.x;
    const int bm0 = blockIdx.x * 128;
    const int wid = tid >> 6, lane = tid & 63;
    const int wm = wid >> 1, wn = wid & 1;
    const int srow = wid * 32 + (lane >> 3);
    const int sc   = lane & 7;

    f32x4 acc[4][4];
    #pragma unroll
    for (int n = 0; n < 4; ++n) {
        float bv = bias[wn * 64 + n * 16 + (lane & 15)];
        #pragma unroll
        for (int m = 0; m < 4; ++m)
            acc[m][n] = (f32x4){bv, bv, bv, bv};
    }

    for (int it = 0; it < KT; ++it) {
        const int k0 = it * 64;
        __syncthreads();
        #pragma unroll
        for (int i = 0; i < 8; ++i) {
            int c = i * 256 + tid;
            int row = c >> 4, c4 = c & 15;
            int grow = bm0 + row; if (grow >= V_N) grow = V_N - 1;
            float4 t = *(const float4*)(A + (size_t)grow * lda + k0 + c4 * 4);
            unsigned lo = (unsigned)f2bf(t.x) | ((unsigned)f2bf(t.y) << 16);
            unsigned hi = (unsigned)f2bf(t.z) | ((unsigned)f2bf(t.w) << 16);
            int e = (row * 64 + c4 * 4) ^ ((row & 7) << 3);
            *(uint2*)&As[e] = make_uint2(lo, hi);
        }
        #pragma unroll
        for (int i = 0; i < 4; ++i) {
            int row = srow + i * 8;
            int g = (sc ^ (row & 7)) << 3;
            gload_lds16(B + (size_t)row * ldb + k0 + g, Bs + (wid * 32 + i * 8) * 64);
        }
        __syncthreads();
        #pragma unroll
        for (int kk = 0; kk < 2; ++kk) {
            bf16x8 a[4], b[4];
            #pragma unroll
            for (int m = 0; m < 4; ++m) {
                int row = wm * 64 + m * 16 + (lane & 15);
                int e = (row * 64 + kk * 32 + (lane >> 4) * 8) ^ ((row & 7) << 3);
                a[m] = *(const bf16x8*)&As[e];
            }
            #pragma unroll
            for (int n = 0; n < 4; ++n) {
                int row = wn * 64 + n * 16 + (lane & 15);
                int e = (row * 64 + kk * 32 + (lane >> 4) * 8) ^ ((row & 7) << 3);
                b[n] = *(const bf16x8*)&Bs[e];
            }
            #pragma unroll
            for (int m = 0; m < 4; ++m)
                #pragma unroll
                for (int n = 0; n < 4; ++n)
                    acc[m][n] = __builtin_amdgcn_mfma_f32_16x16x32_bf16(
                        a[m], b[n], acc[m][n], 0, 0, 0);
        }
    }

    __syncthreads();
    #pragma unroll
    for (int m = 0; m < 4; ++m) {
        #pragma unroll
        for (int j = 0; j < 4; ++j) {
            int row = wm * 64 + m * 16 + (lane >> 4) * 4 + j;
            #pragma unroll
            for (int n = 0; n < 4; ++n) {
                int colx = wn * 64 + n * 16 + (lane & 15);
                float v = fmaxf(acc[m][n][j], 0.f);
                Smem[row * 128 + (((colx >> 3) ^ (row & 7)) << 3) + (colx & 7)] =
                    (short)f2bf(v);
            }
        }
    }
    __syncthreads();
    #pragma unroll
    for (int i = 0; i < 8; ++i) {
        int c = i * 256 + tid;
        int r = c >> 4, c8 = c & 15;
        int grow = bm0 + r;
        if (grow < V_N)
            *(uint4*)&C[(size_t)grow * ldc + c8 * 8] =
                *(const uint4*)&Smem[r * 128 + (c8 ^ (r & 7)) * 8];
    }
}

// ---------------------------------------------------------------------------
// Neighbor sum: s[v] = sum_{u in adj(v)} x[u]  (bf16 io, fp32 accum).
// One 16-lane group per vertex, uint4 per lane (full 256B row per load);
// 4-way + 2-way unrolled neighbors. No LDS -> max occupancy.
// ---------------------------------------------------------------------------
__global__ __launch_bounds__(256) void agg_sum_kernel(
    const short* __restrict__ x, const int* __restrict__ rowp,
    const int* __restrict__ col, short* __restrict__ s)
{
    int g  = (blockIdx.x * 256 + threadIdx.x) >> 4;   // group id = vertex
    int il = threadIdx.x & 15;
    if (g >= V_N) return;
    int st = rowp[g], en = rowp[g + 1];
    float a[8] = {0.f, 0.f, 0.f, 0.f, 0.f, 0.f, 0.f, 0.f};
    int p = st;
    for (; p + 4 <= en; p += 4) {
        int u0 = col[p], u1 = col[p + 1], u2 = col[p + 2], u3 = col[p + 3];
        uint4 q0 = *(const uint4*)(x + (size_t)u0 * 128 + il * 8);
        uint4 q1 = *(const uint4*)(x + (size_t)u1 * 128 + il * 8);
        uint4 q2 = *(const uint4*)(x + (size_t)u2 * 128 + il * 8);
        uint4 q3 = *(const uint4*)(x + (size_t)u3 * 128 + il * 8);
        acc8(a, q0); acc8(a, q1); acc8(a, q2); acc8(a, q3);
    }
    if (p + 2 <= en) {
        int u0 = col[p], u1 = col[p + 1];
        uint4 q0 = *(const uint4*)(x + (size_t)u0 * 128 + il * 8);
        uint4 q1 = *(const uint4*)(x + (size_t)u1 * 128 + il * 8);
        acc8(a, q0); acc8(a, q1);
        p += 2;
    }
    if (p < en) {
        uint4 q = *(const uint4*)(x + (size_t)col[p] * 128 + il * 8);
        acc8(a, q);
    }
    uint4 w;
    w.x = (unsigned)f2bf(a[0]) | ((unsigned)f2bf(a[1]) << 16);
    w.y = (unsigned)f2bf(a[2]) | ((unsigned)f2bf(a[3]) << 16);
    w.z = (unsigned)f2bf(a[4]) | ((unsigned)f2bf(a[5]) << 16);
    w.w = (unsigned)f2bf(a[6]) | ((unsigned)f2bf(a[7]) << 16);
    *(uint4*)(s + (size_t)g * 128 + il * 8) = w;
}

// ---------------------------------------------------------------------------
// GraphConv GEMM (in-place): X[v] = relu( [S[v]|X[v]] @ B^T + b0 + deg*b1
//   (+ L0: W0v.verts[v] + W1v.sv[v]) ),  K=256, N=128.
// VOUT (last layer): out[v] from acc registers in fp32 (validated round 9/10).
// ---------------------------------------------------------------------------
template<bool L0, bool VOUT>
__global__ __launch_bounds__(256) void gconv_mfma_kernel(
    short* __restrict__ X,                     // [V][128] bf16 (A and C)
    const short* __restrict__ S,               // [V][128] bf16
    const short* __restrict__ B,               // [128][256] bf16
    const float* __restrict__ b0, const float* __restrict__ b1,
    const int* __restrict__ deg,
    const float* __restrict__ verts,           // L0 only
    const float* __restrict__ sv,              // [V][4] f32, L0 only
    const float* __restrict__ Wv,              // [128][8] f32, L0 only
    const float* __restrict__ voW,             // [3][128] f32, VOUT only
    const float* __restrict__ vob,             // [3] f32, VOUT only
    float* __restrict__ out)                   // [V][3] f32, VOUT only
{
    __shared__ short Smem[128 * 128];
    short* As = Smem;
    short* Bs = Smem + 128 * 64;
    const int tid = threadIdx.x;
    const int bm0 = blockIdx.x * 128;
    const int wid = tid >> 6, lane = tid & 63;
    const int wm = wid >> 1, wn = wid & 1;
    const int srow = wid * 32 + (lane >> 3);
    const int sc   = lane & 7;

    f32x4 acc[4][4] = {};

    for (int it = 0; it < 4; ++it) {
        const short* Ap = (it < 2) ? S : X;
        const int k0 = (it & 1) * 64;
        __syncthreads();
        #pragma unroll
        for (int i = 0; i < 4; ++i) {
            int row = srow + i * 8;
            int g = (sc ^ (row & 7)) << 3;
            int grow = bm0 + row; if (grow >= V_N) grow = V_N - 1;
            gload_lds16(Ap + (size_t)grow * 128 + k0 + g, As + (wid * 32 + i * 8) * 64);
            gload_lds16(B + (size_t)row * 256 + it * 64 + g, Bs + (wid * 32 + i * 8) * 64);
        }
        __syncthreads();
        #pragma unroll
        for (int kk = 0; kk < 2; ++kk) {
            bf16x8 a[4], b[4];
            #pragma unroll
            for (int m = 0; m < 4; ++m) {
                int row = wm * 64 + m * 16 + (lane & 15);
                int e = (row * 64 + kk * 32 + (lane >> 4) * 8) ^ ((row & 7) << 3);
                a[m] = *(const bf16x8*)&As[e];
            }
            #pragma unroll
            for (int n = 0; n < 4; ++n) {
                int row = wn * 64 + n * 16 + (lane & 15);
                int e = (row * 64 + kk * 32 + (lane >> 4) * 8) ^ ((row & 7) << 3);
                b[n] = *(const bf16x8*)&Bs[e];
            }
            #pragma unroll
            for (int m = 0; m < 4; ++m)
                #pragma unroll
                for (int n = 0; n < 4; ++n)
                    acc[m][n] = __builtin_amdgcn_mfma_f32_16x16x32_bf16(
                        a[m], b[n], acc[m][n], 0, 0, 0);
        }
    }

    // bias / L0 weight preload (col-dependent)
    float bb0[4], bb1[4];
    float w0v[4][3], w1v[4][3];
    #pragma unroll
    for (int n = 0; n < 4; ++n) {
        int colx = wn * 64 + n * 16 + (lane & 15);
        bb0[n] = b0[colx]; bb1[n] = b1[colx];
        if (L0) {
            #pragma unroll
            for (int k = 0; k < 3; ++k) {
                w0v[n][k] = Wv[colx * 8 + k];
                w1v[n][k] = Wv[colx * 8 + 4 + k];
            }
        }
    }

    if constexpr (VOUT) {
        // ---- fused final projection, all fp32 from registers ----
        float wv0[4], wv1[4], wv2[4];
        #pragma unroll
        for (int n = 0; n < 4; ++n) {
            int colx = wn * 64 + n * 16 + (lane & 15);
            wv0[n] = voW[colx]; wv1[n] = voW[128 + colx]; wv2[n] = voW[256 + colx];
        }
        __syncthreads();                 // As/Bs reads complete; reuse Smem
        float* vsum = (float*)Smem;      // [128][4] f32
        for (int q = tid; q < 512; q += 256) vsum[q] = 0.f;
        __syncthreads();
        #pragma unroll
        for (int m = 0; m < 4; ++m) {
            #pragma unroll
            for (int j = 0; j < 4; ++j) {
                int row = wm * 64 + m * 16 + (lane >> 4) * 4 + j;
                int grow = bm0 + row; if (grow >= V_N) grow = V_N - 1;
                float dv = (float)deg[grow];
                float p0 = 0.f, p1 = 0.f, p2 = 0.f;
                #pragma unroll
                for (int n = 0; n < 4; ++n) {
                    float v = fmaxf(acc[m][n][j] + bb0[n] + dv * bb1[n], 0.f);
                    p0 += v * wv0[n]; p1 += v * wv1[n]; p2 += v * wv2[n];
                }
                #pragma unroll
                for (int off = 1; off < 16; off <<= 1) {
                    p0 += __shfl_xor(p0, off);
                    p1 += __shfl_xor(p1, off);
                    p2 += __shfl_xor(p2, off);
                }
                if ((lane & 15) == 0) {   // 2 contributors/row (wn pair)
                    atomicAdd(&vsum[row * 4 + 0], p0);
                    atomicAdd(&vsum[row * 4 + 1], p1);
                    atomicAdd(&vsum[row * 4 + 2], p2);
                }
            }
        }
        __syncthreads();
        if (tid < 128) {
            int grow = bm0 + tid;
            if (grow < V_N) {
                out[3 * grow]     = vsum[tid * 4]     + vob[0];
                out[3 * grow + 1] = vsum[tid * 4 + 1] + vob[1];
                out[3 * grow + 2] = vsum[tid * 4 + 2] + vob[2];
            }
        }
        return;
    }

    __syncthreads();
    #pragma unroll
    for (int m = 0; m < 4; ++m) {
        #pragma unroll
        for (int j = 0; j < 4; ++j) {
            int row = wm * 64 + m * 16 + (lane >> 4) * 4 + j;
            int grow = bm0 + row; if (grow >= V_N) grow = V_N - 1;
            float dv = (float)deg[grow];
            float vx = 0.f, vy = 0.f, vz = 0.f;
            float4 s4 = {0.f, 0.f, 0.f, 0.f};
            if (L0) {
                vx = verts[3 * grow]; vy = verts[3 * grow + 1]; vz = verts[3 * grow + 2];
                s4 = *(const float4*)&sv[grow * 4];
            }
            #pragma unroll
            for (int n = 0; n < 4; ++n) {
                int colx = wn * 64 + n * 16 + (lane & 15);
                float v = acc[m][n][j] + bb0[n] + dv * bb1[n];
                if (L0)
                    v += w0v[n][0] * vx + w0v[n][1] * vy + w0v[n][2] * vz
                       + w1v[n][0] * s4.x + w1v[n][1] * s4.y + w1v[n][2] * s4.z;
                v = fmaxf(v, 0.f);
                Smem[row * 128 + (((colx >> 3) ^ (row & 7)) << 3) + (colx & 7)] =
                    (short)f2bf(v);
            }
        }
    }
    __syncthreads();
    #pragma unroll
    for (int i = 0; i < 8; ++i) {
        int c = i * 256 + tid;
        int r = c >> 4, c8 = c & 15;
        int grow = bm0 + r;
        if (grow < V_N)
            *(uint4*)&X[(size_t)grow * 128 + c8 * 8] =
                *(const uint4*)&Smem[r * 128 + (c8 ^ (r & 7)) * 8];
    }
}

// ------------------------- prep: weights + sv (one kernel) ----------------
__global__ __launch_bounds__(256) void prep_all_kernel(
    const float* __restrict__ bnW,
    const float* __restrict__ g0W0, const float* __restrict__ g0W1,
    const float* __restrict__ gW0,  const float* __restrict__ gW1,
    const float* __restrict__ verts,
    const int* __restrict__ rowp, const int* __restrict__ colv,
    short* __restrict__ bnWb, short* __restrict__ Wc,
    float* __restrict__ Wv, float* __restrict__ sv)
{
    int i = blockIdx.x * 256 + threadIdx.x;
    if (i < 128 * FEAT) bnWb[i] = (short)f2bf(bnW[i]);
    if (i < 8 * 128 * 256) {
        int l = i >> 15, r = (i >> 8) & 127, c = i & 255;
        float v;
        if (l == 0)
            v = (c < 128) ? g0W1[r * 131 + c] : g0W0[r * 131 + (c - 128)];
        else {
            int ll = l - 1;
            v = (c < 128) ? gW1[((size_t)ll * 128 + r) * 128 + c]
                          : gW0[((size_t)ll * 128 + r) * 128 + (c - 128)];
        }
        Wc[i] = (short)f2bf(v);
    }
    if (i < 128) {
        Wv[i * 8 + 0] = g0W0[i * 131 + 128];
        Wv[i * 8 + 1] = g0W0[i * 131 + 129];
        Wv[i * 8 + 2] = g0W0[i * 131 + 130];
        Wv[i * 8 + 3] = 0.f;
        Wv[i * 8 + 4] = g0W1[i * 131 + 128];
        Wv[i * 8 + 5] = g0W1[i * 131 + 129];
        Wv[i * 8 + 6] = g0W1[i * 131 + 130];
        Wv[i * 8 + 7] = 0.f;
    }
    if (i < V_N) {
        float sx = 0.f, sy = 0.f, sz = 0.f;
        int en = rowp[i + 1];
        for (int p = rowp[i]; p < en; ++p) {
            int u = colv[p];
            sx += verts[3 * u]; sy += verts[3 * u + 1]; sz += verts[3 * u + 2];
        }
        float4 o = {sx, sy, sz, 0.f};
        *(float4*)&sv[(size_t)i * 4] = o;
    }
}

// ------------------------- CSR construction -------------------------------
__global__ void deg_count_kernel(const int* __restrict__ edges, int* __restrict__ deg)
{
    int e = blockIdx.x * blockDim.x + threadIdx.x;
    if (e >= E_N) return;
    int i = edges[2 * e], j = edges[2 * e + 1];
    atomicAdd(&deg[i], 1);
    atomicAdd(&deg[j], 1);
}

__global__ __launch_bounds__(1024) void scan_block_kernel(
    const int* __restrict__ deg, int* __restrict__ excl, int* __restrict__ bsum)
{
    __shared__ int sdata[1024];
    int t = threadIdx.x;
    int base = blockIdx.x * 1024;
    int val = (base + t < V_N) ? deg[base + t] : 0;
    sdata[t] = val; __syncthreads();
    for (int off = 1; off < 1024; off <<= 1) {
        int tmp = (t >= off) ? sdata[t - off] : 0;
        __syncthreads();
        sdata[t] += tmp;
        __syncthreads();
    }
    if (base + t < V_N) excl[base + t] = sdata[t] - val;
    if (t == 1023) bsum[blockIdx.x] = sdata[1023];
}

__global__ __launch_bounds__(256) void scan_bsum_kernel(
    const int* __restrict__ bsum, int* __restrict__ boff)
{
    __shared__ int sdata[256];
    int t = threadIdx.x;
    int val = (t < NSCAN) ? bsum[t] : 0;
    sdata[t] = val; __syncthreads();
    for (int off = 1; off < 256; off <<= 1) {
        int tmp = (t >= off) ? sdata[t - off] : 0;
        __syncthreads();
        sdata[t] += tmp;
        __syncthreads();
    }
    if (t < NSCAN) boff[t] = sdata[t] - val;
    if (t == 255) boff[NSCAN] = sdata[255];
}

__global__ void scan_add_kernel(const int* __restrict__ boff,
                                int* __restrict__ rowp, int* __restrict__ cur)
{
    int i = blockIdx.x * blockDim.x + threadIdx.x;
    if (i < V_N) {
        int r = rowp[i] + boff[i >> 10];
        rowp[i] = r;
        cur[i] = r;
    } else if (i == V_N) {
        rowp[V_N] = boff[NSCAN];
    }
}

__global__ void fill_kernel(const int* __restrict__ edges,
                            int* __restrict__ cur, int* __restrict__ col)
{
    int e = blockIdx.x * blockDim.x + threadIdx.x;
    if (e >= E_N) return;
    int i = edges[2 * e], j = edges[2 * e + 1];
    col[atomicAdd(&cur[i], 1)] = j;
    col[atomicAdd(&cur[j], 1)] = i;
}

// ---------------------------------------------------------------------------
extern "C" void kernel_launch(void* const* d_in, const int* in_sizes, int n_in,
                              void* d_out, int out_size, void* d_ws, size_t ws_size,
                              hipStream_t stream)
{
    const float* img   = (const float*)d_in[0];
    const float* verts = (const float*)d_in[1];
    const int*   edges = (const int*)  d_in[2];
    const float* bnW   = (const float*)d_in[3];
    const float* bnb   = (const float*)d_in[4];
    const float* g0W0  = (const float*)d_in[5];
    const float* g0b0  = (const float*)d_in[6];
    const float* g0W1  = (const float*)d_in[7];
    const float* g0b1  = (const float*)d_in[8];
    const float* gW0   = (const float*)d_in[9];
    const float* gb0   = (const float*)d_in[10];
    const float* gW1   = (const float*)d_in[11];
    const float* gb1   = (const float*)d_in[12];
    const float* voW   = (const float*)d_in[13];
    const float* vob   = (const float*)d_in[14];
    float* out = (float*)d_out;

    // workspace layout (16B-aligned segments)
    short* xa   = (short*)d_ws;                       // V*128 bf16
    short* sb   = xa   + (size_t)V_N * 128;           // V*128 bf16
    short* bnWb = sb   + (size_t)V_N * 128;           // 128*960
    short* Wc   = bnWb + 128 * FEAT;                  // 8*128*256
    float* Wv   = (float*)(Wc + 8 * 128 * 256);       // 128*8
    float* sv   = Wv   + 128 * 8;                     // V*4
    int*   deg  = (int*)(sv + (size_t)V_N * 4);       // V
    int*   rowp = deg  + V_N;                         // V+1
    int*   cur  = rowp + V_N + 1;                     // V
    int*   bsum = cur  + V_N;                         // 256
    int*   boff = bsum + 256;                         // NSCAN+1
    int*   col  = boff + 257;                         // 2E

    // ---- CSR build ----
    hipMemsetAsync(deg, 0, V_N * sizeof(int), stream);
    deg_count_kernel<<<(E_N + 255) / 256, 256, 0, stream>>>(edges, deg);
    scan_block_kernel<<<NSCAN, 1024, 0, stream>>>(deg, rowp, bsum);
    scan_bsum_kernel<<<1, 256, 0, stream>>>(bsum, boff);
    scan_add_kernel<<<(V_N + 256) / 256, 256, 0, stream>>>(boff, rowp, cur);
    fill_kernel<<<(E_N + 255) / 256, 256, 0, stream>>>(edges, cur, col);

    // ---- prep (weights + sv; after CSR) ----
    prep_all_kernel<<<(8 * 128 * 256 + 255) / 256, 256, 0, stream>>>(
        bnW, g0W0, g0W1, gW0, gW1, verts, rowp, col, bnWb, Wc, Wv, sv);

    const int MB = (V_N + 127) / 128;          // 1563
    const int AGGB = (V_N * 16 + 255) / 256;   // 12500

    // ---- backbone: img(fp32,K=960) @ bnW^T -> xa (relu) ----
    backbone_mfma_kernel<15><<<MB, 256, 0, stream>>>(img, FEAT, bnWb, FEAT, bnb, xa, 128);

    // ---- layer 0 (verts via epilogue) ----
    agg_sum_kernel<<<AGGB, 256, 0, stream>>>(xa, rowp, col, sb);
    gconv_mfma_kernel<true, false><<<MB, 256, 0, stream>>>(
        xa, sb, Wc, g0b0, g0b1, deg, verts, sv, Wv, nullptr, nullptr, nullptr);

    // ---- layers 1..6 (in-place on xa) ----
    for (int l = 1; l < NREST; ++l) {
        agg_sum_kernel<<<AGGB, 256, 0, stream>>>(xa, rowp, col, sb);
        gconv_mfma_kernel<false, false><<<MB, 256, 0, stream>>>(
            xa, sb, Wc + (size_t)l * 128 * 256,
            gb0 + (size_t)(l - 1) * 128, gb1 + (size_t)(l - 1) * 128,
            deg, nullptr, nullptr, nullptr, nullptr, nullptr, nullptr);
    }

    // ---- layer 7 + fused final projection (fp32 register path) ----
    agg_sum_kernel<<<AGGB, 256, 0, stream>>>(xa, rowp, col, sb);
    gconv_mfma_kernel<false, true><<<MB, 256, 0, stream>>>(
        xa, sb, Wc + (size_t)NREST * 128 * 256,
        gb0 + (size_t)(NREST - 1) * 128, gb1 + (size_t)(NREST - 1) * 128,
        deg, nullptr, nullptr, nullptr, voW, vob, out);
}